// Round 1
// baseline (318.971 us; speedup 1.0000x reference)
//
#include <hip/hip_runtime.h>

// LocalLayer: y = x @ W^T + b, W banded: output window k (16 outputs)
// reads input cols [16k-32, 16k+32) clamped to [0,4096). Banded GEMM =
// 4.3 GFLOP (vs 275 dense) -> pure memory reshuffle, HBM/latency-bound.
//
// R1 change vs baseline (92us gemm, Occ 36%): occupancy was LDS-capped at
// 4 blocks/CU (39.9KB xs). Halve block rows (64->32, LDS 19968B) and use
// 512-thread blocks (8 waves: 2 m-tiles x 4 window-quarters, acc=16 regs)
// -> 4 blocks/CU * 512 thr = 2048 thr/CU = 100% occupancy cap.
// __launch_bounds__(512,8) pins the <=64-reg budget that makes it real.

typedef __attribute__((ext_vector_type(8))) short short8;
typedef __attribute__((ext_vector_type(4))) float f32x4;
typedef __attribute__((ext_vector_type(4))) unsigned short us4;

#define IN_F 4096
#define OUT_F 4096
#define NROWS 8192
#define ROWS 32                 // batch rows per block
#define GW 16                   // windows per block (256 output cols)
#define WPW 4                   // windows per wave
#define BAND (GW * 16 + 48)     // 304 input cols covered by a window group
#define LSTRIDE 312             // LDS row stride (bf16): 16B-aligned, stride_dw%8==4 -> 2-way (free)
#define V4 (BAND / 4)           // 76 float4 per staged row

__device__ __forceinline__ unsigned short f2bf(float f) {
  unsigned int u = __float_as_uint(f);
  u += 0x7FFFu + ((u >> 16) & 1u);   // round-to-nearest-even
  return (unsigned short)(u >> 16);
}

// Pack banded W into MFMA B-fragment order, bf16. (unchanged from baseline)
// Fragment f = win*2 + t (t = K-half). Lane: n = lane&15, quad = lane>>4,
// k = quad*8 + j. W column = win*16 - 32 + t*32 + k, zero outside [0, IN_F).
__global__ void pack_w_kernel(const float* __restrict__ W,
                              unsigned short* __restrict__ Wp) {
  int tid = blockIdx.x * 256 + threadIdx.x;  // 32768 threads total
  int lane = tid & 63;
  int t = (tid >> 6) & 1;
  int win = tid >> 7;
  int n = lane & 15, quad = lane >> 4;
  int o = win * 16 + n;
  int cbase = win * 16 - 32 + t * 32 + quad * 8;
  short8 h;
#pragma unroll
  for (int j = 0; j < 8; ++j) {
    int c = cbase + j;
    float v = (c >= 0 && c < IN_F) ? W[o * IN_F + c] : 0.0f;
    h[j] = (short)f2bf(v);
  }
  *(short8*)(Wp + (size_t)tid * 8) = h;
}

__global__ __launch_bounds__(512, 8) void local_gemm_kernel(
    const float* __restrict__ x, const unsigned short* __restrict__ Wp,
    const float* __restrict__ bias, float* __restrict__ out) {
  __shared__ unsigned short xs[ROWS * LSTRIDE];  // 19968 B -> 4 blocks/CU (thread-limited)
  const int tid = threadIdx.x;
  const int row0 = blockIdx.x * ROWS;
  const int wg = blockIdx.y;                 // window group (16 windows)
  const int colstart = wg * (GW * 16) - 32;  // may be <0 (wg=0) or run past 4096 (wg=15)

  // Stage x band: fp32 global -> bf16 LDS. 16 threads per row, 5 chunks of
  // 16 float4 (last partial). No integer div; consecutive threads read
  // consecutive float4 -> 256B/row segments. Edge chunks zero-filled
  // (packed W is 0 there anyway).
  {
    const int r = tid >> 4;                  // 0..31
    const int cb = tid & 15;
    const float* xr = x + (size_t)(row0 + r) * IN_F + colstart;
#pragma unroll
    for (int i = 0; i < 5; ++i) {
      int c4 = cb + i * 16;
      if (c4 < V4) {
        int gc = colstart + c4 * 4;
        float4 v = make_float4(0.f, 0.f, 0.f, 0.f);
        if (gc >= 0 && gc < IN_F) v = *(const float4*)(xr + c4 * 4);
        us4 h = {f2bf(v.x), f2bf(v.y), f2bf(v.z), f2bf(v.w)};
        *(us4*)(xs + r * LSTRIDE + c4 * 4) = h;
      }
    }
  }
  __syncthreads();

  const int lane = tid & 63;
  const int wave = tid >> 6;   // 8 waves
  const int wavem = wave & 1;  // m-tile (16 rows)
  const int wavew = wave >> 1; // window quarter (4 windows)
  const int n16 = lane & 15;
  const int quad = lane >> 4;

  f32x4 acc[WPW];
#pragma unroll
  for (int i = 0; i < WPW; ++i) {
    float bv = bias[wg * 256 + (wavew * WPW + i) * 16 + n16];  // bias per output col
    acc[i] = (f32x4){bv, bv, bv, bv};
  }

  const short8* wpv = (const short8*)Wp;
  const unsigned short* xrow = xs + (wavem * 16 + n16) * LSTRIDE + quad * 8;
#pragma unroll
  for (int i = 0; i < WPW; ++i) {
    int w = wavew * WPW + i;
    int win = wg * GW + w;
    // B fragments: coalesced 16 B/lane, L2-resident (512 KB total)
    short8 b0 = wpv[(win * 2 + 0) * 64 + lane];
    short8 b1 = wpv[(win * 2 + 1) * 64 + lane];
    // A fragments: ds_read_b128, window w band starts at local col w*16
    short8 a0 = *(const short8*)(xrow + w * 16);
    short8 a1 = *(const short8*)(xrow + w * 16 + 32);
    acc[i] = __builtin_amdgcn_mfma_f32_16x16x32_bf16(a0, b0, acc[i], 0, 0, 0);
    acc[i] = __builtin_amdgcn_mfma_f32_16x16x32_bf16(a1, b1, acc[i], 0, 0, 0);
  }

  // C/D layout: col = lane&15, row = quad*4 + reg  [m89]
  float* op = out + (size_t)(row0 + wavem * 16 + quad * 4) * OUT_F + wg * 256 + n16;
#pragma unroll
  for (int i = 0; i < WPW; ++i) {
#pragma unroll
    for (int r = 0; r < 4; ++r)
      op[r * OUT_F + (wavew * WPW + i) * 16] = acc[i][r];
  }
}

extern "C" void kernel_launch(void* const* d_in, const int* in_sizes, int n_in,
                              void* d_out, int out_size, void* d_ws, size_t ws_size,
                              hipStream_t stream) {
  const float* x = (const float*)d_in[0];
  const float* W = (const float*)d_in[1];
  const float* b = (const float*)d_in[2];
  // d_in[3] = mask, unused (band structure is compile-time known)
  float* out = (float*)d_out;
  unsigned short* Wp = (unsigned short*)d_ws;  // 256*2*64*8*2 = 512 KB

  hipLaunchKernelGGL(pack_w_kernel, dim3(128), dim3(256), 0, stream, W, Wp);
  hipLaunchKernelGGL(local_gemm_kernel, dim3(NROWS / ROWS, 256 / GW), dim3(512),
                     0, stream, x, Wp, b, out);
}